// Round 2
// baseline (245.103 us; speedup 1.0000x reference)
//
#include <hip/hip_runtime.h>

// LATTE forward, algebraically reduced:
//   message = v[dst]  =>  segment-softmax weights sum to 1  =>  h_m = v * (in_deg_m>0)
//   => k=feat@Wl, attn_l/r, src* are dead.
//   Relation beta: softmax over HEADS (axis=2 of [N,M+1,H]); all f_r=1 relations share
//   logits z1[h]=lrelu(s_l+s_r) => gate g[n,h] = cnt[n] * softmax_h(z1)[h], cnt=1+f0+f1+f2.
//   o = v*g; LayerNorm; ReLU.

#define NN 50000
#define KDIM 256
#define DDIM 256
#define EE 800000
#define NEG 0.2f
#define EPSV 1e-5f

__global__ __launch_bounds__(256) void flags_kernel(
    const int* __restrict__ d0, const int* __restrict__ d1,
    const int* __restrict__ d2, unsigned char* __restrict__ fl)
{
    int i = blockIdx.x * 256 + threadIdx.x;
    if (i < EE) {
        fl[d0[i]] = 1;               // benign write races: all write 1
        fl[NN + d1[i]] = 1;
        fl[2 * NN + d2[i]] = 1;
    }
}

// v = feat @ Wr + br : [50000 x 256] = [50000 x 256][256 x 256]
// BM=128, BN=64, BK=16, 256 threads, each computes 8x4.
__global__ __launch_bounds__(256) void gemm_kernel(
    const float* __restrict__ A, const float* __restrict__ B,
    const float* __restrict__ bias, float* __restrict__ V)
{
    __shared__ float As[16][132];   // [k][row], padded
    __shared__ float Bs[16][64];    // [k][col]
    const int tid = threadIdx.x;
    const int tx = tid & 15, ty = tid >> 4;
    const int row0 = blockIdx.x * 128;
    const int col0 = blockIdx.y * 64;

    float acc[8][4];
#pragma unroll
    for (int i = 0; i < 8; ++i)
#pragma unroll
        for (int j = 0; j < 4; ++j) acc[i][j] = 0.f;

    const int aidx0 = tid * 2;
    const int lb_row = tid >> 4, lb_col = (tid & 15) * 4;

    for (int kk = 0; kk < KDIM; kk += 16) {
#pragma unroll
        for (int q = 0; q < 2; ++q) {
            int idx = aidx0 + q;
            int r = idx >> 2, c4 = (idx & 3) * 4;
            int ar = row0 + r;
            float4 a4 = make_float4(0.f, 0.f, 0.f, 0.f);
            if (ar < NN)
                a4 = *reinterpret_cast<const float4*>(&A[ar * KDIM + kk + c4]);
            As[c4 + 0][r] = a4.x;
            As[c4 + 1][r] = a4.y;
            As[c4 + 2][r] = a4.z;
            As[c4 + 3][r] = a4.w;
        }
        float4 b4 = *reinterpret_cast<const float4*>(&B[(kk + lb_row) * DDIM + col0 + lb_col]);
        *reinterpret_cast<float4*>(&Bs[lb_row][lb_col]) = b4;
        __syncthreads();
#pragma unroll
        for (int k = 0; k < 16; ++k) {
            float4 av0 = *reinterpret_cast<const float4*>(&As[k][ty * 8]);
            float4 av1 = *reinterpret_cast<const float4*>(&As[k][ty * 8 + 4]);
            float4 bv  = *reinterpret_cast<const float4*>(&Bs[k][tx * 4]);
            float a[8] = {av0.x, av0.y, av0.z, av0.w, av1.x, av1.y, av1.z, av1.w};
            float b[4] = {bv.x, bv.y, bv.z, bv.w};
#pragma unroll
            for (int i = 0; i < 8; ++i)
#pragma unroll
                for (int j = 0; j < 4; ++j)
                    acc[i][j] = fmaf(a[i], b[j], acc[i][j]);
        }
        __syncthreads();
    }
    float4 bia = *reinterpret_cast<const float4*>(&bias[col0 + tx * 4]);
#pragma unroll
    for (int i = 0; i < 8; ++i) {
        int r = row0 + ty * 8 + i;
        if (r < NN) {
            float4 o;
            o.x = acc[i][0] + bia.x;
            o.y = acc[i][1] + bia.y;
            o.z = acc[i][2] + bia.z;
            o.w = acc[i][3] + bia.w;
            *reinterpret_cast<float4*>(&V[r * DDIM + col0 + tx * 4]) = o;
        }
    }
}

__device__ __forceinline__ float lrelu(float x) { return x > 0.f ? x : NEG * x; }

// One wave per node (4 nodes / 256-thread block). lane holds dims 4*lane..4*lane+3,
// head = lane>>4 (16 lanes per head, C=64 channels/head). In-place on V.
__global__ __launch_bounds__(256) void epilogue_kernel(
    float* __restrict__ V, const unsigned char* __restrict__ fl,
    const float* __restrict__ rl, const float* __restrict__ rr,
    const float* __restrict__ gamma, const float* __restrict__ beta)
{
    const int lane = threadIdx.x & 63;
    const int wave = threadIdx.x >> 6;
    const int node = blockIdx.x * 4 + wave;
    const int d = lane * 4;
    float4 v = *reinterpret_cast<const float4*>(&V[node * DDIM + d]);
    float4 a = *reinterpret_cast<const float4*>(&rl[d]);   // rel_attn_l flat [H*C]=256
    float4 b = *reinterpret_cast<const float4*>(&rr[d]);
    float pl = v.x * a.x + v.y * a.y + v.z * a.z + v.w * a.w;
    float pr = v.x * b.x + v.y * b.y + v.z * b.z + v.w * b.w;
#pragma unroll
    for (int off = 1; off < 16; off <<= 1) {   // per-head (16-lane group) dot reduction
        pl += __shfl_xor(pl, off, 64);
        pr += __shfl_xor(pr, off, 64);
    }
    // z1[h] = lrelu(s_l[h] + s_r[h]); softmax over the 4 heads (cross-group shuffles)
    float z1 = lrelu(pl + pr);
    float mx = z1;
    mx = fmaxf(mx, __shfl_xor(mx, 16, 64));
    mx = fmaxf(mx, __shfl_xor(mx, 32, 64));
    float e = __expf(z1 - mx);
    float se = e;
    se += __shfl_xor(se, 16, 64);
    se += __shfl_xor(se, 32, 64);
    const float f0 = fl[node] ? 1.f : 0.f;
    const float f1 = fl[NN + node] ? 1.f : 0.f;
    const float f2 = fl[2 * NN + node] ? 1.f : 0.f;
    const float cnt = 1.f + f0 + f1 + f2;
    const float g = cnt * e / se;

    float ox = v.x * g, oy = v.y * g, oz = v.z * g, ow = v.w * g;
    float s = ox + oy + oz + ow;
    float s2 = ox * ox + oy * oy + oz * oz + ow * ow;
#pragma unroll
    for (int off = 1; off < 64; off <<= 1) {   // full-wave LN reduction over 256 dims
        s += __shfl_xor(s, off, 64);
        s2 += __shfl_xor(s2, off, 64);
    }
    float mu = s * (1.f / 256.f);
    float var = s2 * (1.f / 256.f) - mu * mu;
    float rstd = rsqrtf(var + EPSV);
    float4 ga = *reinterpret_cast<const float4*>(&gamma[d]);
    float4 be = *reinterpret_cast<const float4*>(&beta[d]);
    float4 o;
    o.x = fmaxf((ox - mu) * rstd * ga.x + be.x, 0.f);
    o.y = fmaxf((oy - mu) * rstd * ga.y + be.y, 0.f);
    o.z = fmaxf((oz - mu) * rstd * ga.z + be.z, 0.f);
    o.w = fmaxf((ow - mu) * rstd * ga.w + be.w, 0.f);
    *reinterpret_cast<float4*>(&V[node * DDIM + d]) = o;
}

extern "C" void kernel_launch(void* const* d_in, const int* in_sizes, int n_in,
                              void* d_out, int out_size, void* d_ws, size_t ws_size,
                              hipStream_t stream) {
    const float* feat = (const float*)d_in[0];
    const float* Wr   = (const float*)d_in[3];
    const float* br   = (const float*)d_in[4];
    const float* rl   = (const float*)d_in[7];
    const float* rr   = (const float*)d_in[8];
    const float* gam  = (const float*)d_in[9];
    const float* bet  = (const float*)d_in[10];
    const int* dst0   = (const int*)d_in[12];
    const int* dst1   = (const int*)d_in[14];
    const int* dst2   = (const int*)d_in[16];
    float* out = (float*)d_out;
    unsigned char* fl = (unsigned char*)d_ws;   // 3*NN bytes scratch (re-poisoned 0xAA -> zero it)

    hipMemsetAsync(fl, 0, 3 * NN, stream);
    flags_kernel<<<(EE + 255) / 256, 256, 0, stream>>>(dst0, dst1, dst2, fl);
    gemm_kernel<<<dim3((NN + 127) / 128, DDIM / 64), 256, 0, stream>>>(feat, Wr, br, out);
    epilogue_kernel<<<NN / 4, 256, 0, stream>>>(out, fl, rl, rr, gam, bet);
}

// Round 3
// 191.754 us; speedup vs baseline: 1.2782x; 1.2782x over previous
//
#include <hip/hip_runtime.h>

// LATTE forward, algebraically reduced (verified R2):
//   h_m = v * (in_deg_m>0); gate g[n,h] = cnt[n]*softmax_h(lrelu(v.rl + v.rr))[h];
//   o = v*g; LayerNorm; ReLU.  v = feat@Wr + br.
// R3: bf16-MFMA GEMM with fused epilogue. A read global->VGPR (wave-private rows),
// B pre-transposed to bf16, LDS-staged (XOR-swizzled) via global_load_lds.

#define NN 50000
#define KDIM 256
#define EE 800000
#define NEG 0.2f
#define EPSV 1e-5f
#define NTILES 3125   // 50000/16 (exact)
#define FLB 3125      // EE/256 (exact)

typedef __attribute__((ext_vector_type(8))) short bf16x8;
typedef __attribute__((ext_vector_type(4))) float f32x4;

__device__ __forceinline__ short f2bf(float f) {   // RNE fp32->bf16
    unsigned u = __float_as_uint(f);
    u += 0x7fff + ((u >> 16) & 1);
    return (short)(u >> 16);
}

__device__ __forceinline__ void ld_g2l_16(void* lds, const void* g) {
    __builtin_amdgcn_global_load_lds(
        (const __attribute__((address_space(1))) unsigned int*)g,
        (__attribute__((address_space(3))) unsigned int*)lds, 16, 0, 0);
}

// blocks [0,FLB): degree flags. blocks [FLB,FLB+256): Wt[n][k] = bf16(Wr[k][n]).
__global__ __launch_bounds__(256) void prep_kernel(
    const int* __restrict__ d0, const int* __restrict__ d1,
    const int* __restrict__ d2, unsigned char* __restrict__ fl,
    const float* __restrict__ Wr, unsigned short* __restrict__ Wt)
{
    int b = blockIdx.x, t = threadIdx.x;
    if (b < FLB) {
        int i = b * 256 + t;
        fl[d0[i]] = 1;                 // benign races: all write 1
        fl[NN + d1[i]] = 1;
        fl[2 * NN + d2[i]] = 1;
    } else {
        int n = b - FLB;
        Wt[n * 256 + t] = (unsigned short)f2bf(Wr[t * 256 + n]);
    }
}

// 512 threads = 8 waves. wave's tile = blockIdx.x + 512*wave (load-balanced);
// tile = 16 rows x 256 cols. mfma 16x16x32 bf16: A[m=lane&15][k=quad*8+j],
// B[k=quad*8+j][n=lane&15], C row=quad*4+reg col=lane&15.
__global__ __launch_bounds__(512, 4) void fused_kernel(
    const float* __restrict__ feat, const unsigned short* __restrict__ Wt,
    const float* __restrict__ br, const float* __restrict__ rl,
    const float* __restrict__ rr, const float* __restrict__ gamma,
    const float* __restrict__ beta, const unsigned char* __restrict__ fl,
    float* __restrict__ out)
{
    // one K-half of B^T: slot s (16B) holds Bs[n][ks*8..+7], n=s>>4, ks=(s&15)^(n&15)
    __shared__ unsigned short Bs[32768];   // 64 KB
    const int t = threadIdx.x;
    const int wave = t >> 6, lane = t & 63;
    const int cl = lane & 15, quad = lane >> 4;
    const int tile = blockIdx.x + 512 * wave;
    const bool act = tile < NTILES;
    const int row0 = tile * 16;

    f32x4 acc[16];
#pragma unroll
    for (int i = 0; i < 16; ++i) acc[i] = (f32x4){0.f, 0.f, 0.f, 0.f};

    const float* arow = feat + (size_t)(act ? (row0 + cl) : 0) * KDIM;

#pragma unroll
    for (int half = 0; half < 2; ++half) {
        if (half) __syncthreads();         // protect LDS before overwrite
        // stage B k-half: 64KB = 4096 slots, 8 slots/thread
#pragma unroll
        for (int c = 0; c < 8; ++c) {
            int s = c * 512 + t;
            int n = s >> 4;
            int ks = (s & 15) ^ (n & 15);
            const unsigned short* g = Wt + n * 256 + half * 128 + ks * 8;
            ld_g2l_16(&Bs[(size_t)(c * 512 + wave * 64) * 8], g);
        }
        __syncthreads();                   // drains vmcnt for the DMA
        if (act) {
#pragma unroll
            for (int kk = 0; kk < 4; ++kk) {
                int k0 = half * 128 + kk * 32 + quad * 8;
                float4 a0 = *reinterpret_cast<const float4*>(arow + k0);
                float4 a1 = *reinterpret_cast<const float4*>(arow + k0 + 4);
                bf16x8 af;
                af[0] = f2bf(a0.x); af[1] = f2bf(a0.y);
                af[2] = f2bf(a0.z); af[3] = f2bf(a0.w);
                af[4] = f2bf(a1.x); af[5] = f2bf(a1.y);
                af[6] = f2bf(a1.z); af[7] = f2bf(a1.w);
                int ks = kk * 4 + quad;
#pragma unroll
                for (int ct = 0; ct < 16; ++ct) {
                    int n = ct * 16 + cl;
                    bf16x8 bf = *reinterpret_cast<const bf16x8*>(
                        &Bs[(size_t)(n * 16 + (ks ^ (n & 15))) * 8]);
                    acc[ct] = __builtin_amdgcn_mfma_f32_16x16x32_bf16(af, bf, acc[ct], 0, 0, 0);
                }
            }
        }
    }
    if (!act) return;

    // ---- fused epilogue (per wave: 16 rows x 256 cols, C-layout) ----
    // bias
#pragma unroll
    for (int ct = 0; ct < 16; ++ct) {
        float bc = br[ct * 16 + cl];
#pragma unroll
        for (int r = 0; r < 4; ++r) acc[ct][r] += bc;
    }
    // per-head dots -> logits z[h][r]
    float z[4][4];
#pragma unroll
    for (int h = 0; h < 4; ++h) {
        float sl[4] = {0, 0, 0, 0}, sr[4] = {0, 0, 0, 0};
#pragma unroll
        for (int j = 0; j < 4; ++j) {
            int ct = h * 4 + j;
            float rlc = rl[ct * 16 + cl], rrc = rr[ct * 16 + cl];
#pragma unroll
            for (int r = 0; r < 4; ++r) {
                sl[r] += acc[ct][r] * rlc;
                sr[r] += acc[ct][r] * rrc;
            }
        }
#pragma unroll
        for (int off = 1; off < 16; off <<= 1)
#pragma unroll
            for (int r = 0; r < 4; ++r) {
                sl[r] += __shfl_xor(sl[r], off, 64);
                sr[r] += __shfl_xor(sr[r], off, 64);
            }
#pragma unroll
        for (int r = 0; r < 4; ++r) {
            float x = sl[r] + sr[r];
            z[h][r] = x > 0.f ? x : NEG * x;
        }
    }
    // softmax over heads + count gate
    float gg[4][4];   // [h][r]
#pragma unroll
    for (int r = 0; r < 4; ++r) {
        float mx = fmaxf(fmaxf(z[0][r], z[1][r]), fmaxf(z[2][r], z[3][r]));
        float e0 = __expf(z[0][r] - mx), e1 = __expf(z[1][r] - mx);
        float e2 = __expf(z[2][r] - mx), e3 = __expf(z[3][r] - mx);
        int rg = row0 + quad * 4 + r;
        float cnt = 1.f + (fl[rg] ? 1.f : 0.f) + (fl[NN + rg] ? 1.f : 0.f)
                        + (fl[2 * NN + rg] ? 1.f : 0.f);
        float inv = cnt / (e0 + e1 + e2 + e3);
        gg[0][r] = e0 * inv; gg[1][r] = e1 * inv;
        gg[2][r] = e2 * inv; gg[3][r] = e3 * inv;
    }
    // gate + LN stats
    float s[4] = {0, 0, 0, 0}, s2[4] = {0, 0, 0, 0};
#pragma unroll
    for (int ct = 0; ct < 16; ++ct) {
        int h = ct >> 2;
#pragma unroll
        for (int r = 0; r < 4; ++r) {
            float o = acc[ct][r] * gg[h][r];
            acc[ct][r] = o;
            s[r] += o;
            s2[r] += o * o;
        }
    }
#pragma unroll
    for (int off = 1; off < 16; off <<= 1)
#pragma unroll
        for (int r = 0; r < 4; ++r) {
            s[r] += __shfl_xor(s[r], off, 64);
            s2[r] += __shfl_xor(s2[r], off, 64);
        }
    float mu[4], rstd[4];
#pragma unroll
    for (int r = 0; r < 4; ++r) {
        mu[r] = s[r] * (1.f / 256.f);
        float var = s2[r] * (1.f / 256.f) - mu[r] * mu[r];
        rstd[r] = rsqrtf(var + EPSV);
    }
    // LN + ReLU + store
#pragma unroll
    for (int ct = 0; ct < 16; ++ct) {
        float ga = gamma[ct * 16 + cl], be = beta[ct * 16 + cl];
#pragma unroll
        for (int r = 0; r < 4; ++r) {
            float v = (acc[ct][r] - mu[r]) * rstd[r] * ga + be;
            out[(size_t)(row0 + quad * 4 + r) * 256 + ct * 16 + cl] = fmaxf(v, 0.f);
        }
    }
}

extern "C" void kernel_launch(void* const* d_in, const int* in_sizes, int n_in,
                              void* d_out, int out_size, void* d_ws, size_t ws_size,
                              hipStream_t stream) {
    const float* feat = (const float*)d_in[0];
    const float* Wr   = (const float*)d_in[3];
    const float* br   = (const float*)d_in[4];
    const float* rl   = (const float*)d_in[7];
    const float* rr   = (const float*)d_in[8];
    const float* gam  = (const float*)d_in[9];
    const float* bet  = (const float*)d_in[10];
    const int* dst0   = (const int*)d_in[12];
    const int* dst1   = (const int*)d_in[14];
    const int* dst2   = (const int*)d_in[16];
    float* out = (float*)d_out;
    unsigned char* fl  = (unsigned char*)d_ws;                    // 150000 B
    unsigned short* Wt = (unsigned short*)((char*)d_ws + 262144); // 128 KB, 16B-aligned

    hipMemsetAsync(fl, 0, 3 * NN, stream);
    prep_kernel<<<FLB + 256, 256, 0, stream>>>(dst0, dst1, dst2, fl, Wr, Wt);
    fused_kernel<<<512, 512, 0, stream>>>(feat, Wt, br, rl, rr, gam, bet, fl, out);
}